// Round 3
// baseline (175.786 us; speedup 1.0000x reference)
//
#include <hip/hip_runtime.h>

// Int8 fake-quant linear (exact integer accumulation):
//   sx = max|x|/128; qx = clamp(rint(x/sx),-128,127)
//   sw = max|w|/127; qw = clamp(rint(w/sw),-127,127)
//   out = mul * (sx*sw*(qx @ qw^T) + bias)
//
// qx/qw are stored PERMUTED in workspace, in LDS chunk-plane order:
//   v4i index = ((blk*32 + kt)*4 + c)*256 + r
//   holds bytes [kt*64 + c*16 .. +15] of row blk*256+r.
// -> staging is a linear contiguous copy (global_load_lds, lane-linear dest)
// -> fragment reads are 32-lane-contiguous (round-1-verified: 0 bank conflicts)

typedef int v4i  __attribute__((ext_vector_type(4)));
typedef int v16i __attribute__((ext_vector_type(16)));

#define MDIM 4096
#define NDIM 8192
#define KDIM 2048
#define NT   (KDIM / 64)   // 32 K-tiles of BK=64 int8

typedef __attribute__((address_space(1))) void* gas_ptr;   // global
typedef __attribute__((address_space(3))) void* las_ptr;   // LDS

// ---------------- init: zero the two absmax slots ----------------
__global__ void init_scales(unsigned* s) {
    if (threadIdx.x < 2) s[threadIdx.x] = 0u;
}

// ---------------- fused absmax over x and w ----------------
#define XBLK 1024
__global__ void absmax2(const float4* __restrict__ x, int nx4,
                        const float4* __restrict__ w, int nw4,
                        unsigned* __restrict__ out) {
    const bool isx = blockIdx.x < XBLK;
    const float4* in = isx ? x : w;
    const int n4 = isx ? nx4 : nw4;
    const int nb = isx ? XBLK : (gridDim.x - XBLK);
    const int b  = isx ? blockIdx.x : (blockIdx.x - XBLK);
    float m = 0.0f;
    for (int i = b * blockDim.x + threadIdx.x; i < n4; i += nb * blockDim.x) {
        float4 v = in[i];
        m = fmaxf(m, fmaxf(fmaxf(fabsf(v.x), fabsf(v.y)),
                           fmaxf(fabsf(v.z), fabsf(v.w))));
    }
#pragma unroll
    for (int off = 32; off > 0; off >>= 1)
        m = fmaxf(m, __shfl_xor(m, off, 64));
    __shared__ float wm[4];
    if ((threadIdx.x & 63) == 0) wm[threadIdx.x >> 6] = m;
    __syncthreads();
    if (threadIdx.x == 0) {
        float mm = fmaxf(fmaxf(wm[0], wm[1]), fmaxf(wm[2], wm[3]));
        atomicMax(out + (isx ? 0 : 1), __float_as_uint(mm));
    }
}

// ---------------- fused quantize into PERMUTED int8 layout ----------------
// idx (v4i units): r = idx&255, c = (idx>>8)&3, kt = (idx>>10)&31, blk = idx>>15
// src: row blk*256+r, float4 base = row*512 + kt*16 + c*4 (4 consecutive float4)
// Writes fully coalesced; reads are 64B-per-lane row-gather (lines fully used).
__global__ void quant2(const float4* __restrict__ x, v4i* __restrict__ qxp,
                       const float4* __restrict__ w, v4i* __restrict__ qwp,
                       const unsigned* __restrict__ scales) {
    const bool isx = blockIdx.x < XBLK;
    const float4* in = isx ? x : w;
    v4i* outp = isx ? qxp : qwp;
    const int total = isx ? (MDIM * KDIM / 16) : (NDIM * KDIM / 16);
    const int nb = isx ? XBLK : (gridDim.x - XBLK);
    const int b  = isx ? blockIdx.x : (blockIdx.x - XBLK);
    const float s  = __uint_as_float(scales[isx ? 0 : 1]) / (isx ? 128.0f : 127.0f);
    const float lo = isx ? -128.0f : -127.0f;
    for (int idx = b * blockDim.x + threadIdx.x; idx < total; idx += nb * blockDim.x) {
        const int r   = idx & 255;
        const int c   = (idx >> 8) & 3;
        const int kt  = (idx >> 10) & 31;
        const int blk = idx >> 15;
        const int row = blk * 256 + r;
        const float4* src = in + (size_t)row * (KDIM / 4) + kt * 16 + c * 4;
        int q[4];
#pragma unroll
        for (int j = 0; j < 4; ++j) {
            float4 v = src[j];
            int b0 = (int)fminf(fmaxf(rintf(v.x / s), lo), 127.0f);
            int b1 = (int)fminf(fmaxf(rintf(v.y / s), lo), 127.0f);
            int b2 = (int)fminf(fmaxf(rintf(v.z / s), lo), 127.0f);
            int b3 = (int)fminf(fmaxf(rintf(v.w / s), lo), 127.0f);
            q[j] = (b0 & 255) | ((b1 & 255) << 8) | ((b2 & 255) << 16) | (b3 << 24);
        }
        v4i qq; qq[0] = q[0]; qq[1] = q[1]; qq[2] = q[2]; qq[3] = q[3];
        outp[idx] = qq;
    }
}

// ---------------- int8 MFMA GEMM, 256x256 tile, 4-deep ring, 2-phase ----------------
// 8 waves (2M x 4N); wave output 128x64 = 4x2 mfma_i32_32x32x32_i8.
// LDS per buffer: A,B each 4 chunk-planes x 256 rows x 16B (16 KB); 4 buffers = 128 KiB.
// Per K-tile: 2 phases (k-step s=0,1). Phase: {6 ds_read_b128 (contiguous,
// conflict-free); stage half of tile kt+3; s_barrier; setprio(1); 8 MFMA;
// setprio(0); s_barrier}. vmcnt(8/4/0) only at tile boundaries (T4).
__global__ __launch_bounds__(512, 2) void gemm_i8(
    const signed char* __restrict__ qxp, const signed char* __restrict__ qwp,
    const float* __restrict__ bias, const float* __restrict__ mulv,
    const unsigned* __restrict__ scales, float* __restrict__ out) {
    __shared__ signed char ldsA[4][16384];
    __shared__ signed char ldsB[4][16384];

    const int t    = threadIdx.x;
    const int lane = t & 63;
    const int ln   = lane & 31;
    const int hi   = lane >> 5;
    const int w    = t >> 6;      // 0..7
    const int wr   = w >> 2;      // 0..1  (M half)
    const int wc   = w & 3;       // 0..3  (N quarter)

    // XCD-aware swizzle: 512 workgroups, 512 % 8 == 0 -> simple bijection.
    const int orig = blockIdx.x;
    const int wg   = ((orig & 7) << 6) | (orig >> 3);
    const int bm   = wg >> 5;     // 0..15
    const int bn   = wg & 31;     // 0..31

    // ---- staging: linear contiguous copy of 16KB tile slabs ----
    const signed char* srcA = qxp + (size_t)bm * (32 * 16384);
    const signed char* srcB = qwp + (size_t)bn * (32 * 16384);
    signed char* dA = &ldsA[0][0] + t * 16;   // wave-uniform base + lane*16
    signed char* dB = &ldsB[0][0] + t * 16;

    auto stageA = [&](int buf, int kt) {
        const signed char* sp = srcA + kt * 16384 + t * 16;
        __builtin_amdgcn_global_load_lds((gas_ptr)sp,          (las_ptr)(dA + buf * 16384),        16, 0, 0);
        __builtin_amdgcn_global_load_lds((gas_ptr)(sp + 8192), (las_ptr)(dA + buf * 16384 + 8192), 16, 0, 0);
    };
    auto stageB = [&](int buf, int kt) {
        const signed char* sp = srcB + kt * 16384 + t * 16;
        __builtin_amdgcn_global_load_lds((gas_ptr)sp,          (las_ptr)(dB + buf * 16384),        16, 0, 0);
        __builtin_amdgcn_global_load_lds((gas_ptr)(sp + 8192), (las_ptr)(dB + buf * 16384 + 8192), 16, 0, 0);
    };

    // ---- fragment offsets (chunk-plane: plane c = 2s+hi, 32-lane contiguous) ----
    const int aOff = (wr * 128 + ln) * 16;   // + mt*512 + plane*4096
    const int bOff = (wc * 64  + ln) * 16;   // + nt*512 + plane*4096

    v16i acc[4][2];
#pragma unroll
    for (int mt = 0; mt < 4; ++mt)
#pragma unroll
        for (int nt = 0; nt < 2; ++nt)
#pragma unroll
            for (int r = 0; r < 16; ++r) acc[mt][nt][r] = 0;

    // ---- prologue: 3 tiles in flight ----
    stageA(0, 0); stageB(0, 0);
    stageA(1, 1); stageB(1, 1);
    stageA(2, 2); stageB(2, 2);
    asm volatile("s_waitcnt vmcnt(8)" ::: "memory");   // tile 0 done
    __builtin_amdgcn_s_barrier();

    for (int kt = 0; kt < NT; ++kt) {
        const int buf = kt & 3;
        const signed char* Ab = &ldsA[buf][0];
        const signed char* Bb = &ldsB[buf][0];

        // ---------- phase 0 (k-step s=0, plane = hi) ----------
        {
            const signed char* A = Ab + hi * 4096;
            const signed char* B = Bb + hi * 4096;
            v4i a0 = *(const v4i*)(A + aOff);
            v4i a1 = *(const v4i*)(A + aOff + 512);
            v4i a2 = *(const v4i*)(A + aOff + 1024);
            v4i a3 = *(const v4i*)(A + aOff + 1536);
            v4i b0 = *(const v4i*)(B + bOff);
            v4i b1 = *(const v4i*)(B + bOff + 512);
            if (kt < NT - 3) stageA((kt + 3) & 3, kt + 3);
            __builtin_amdgcn_s_barrier();
            __builtin_amdgcn_s_setprio(1);
            acc[0][0] = __builtin_amdgcn_mfma_i32_32x32x32_i8(a0, b0, acc[0][0], 0, 0, 0);
            acc[0][1] = __builtin_amdgcn_mfma_i32_32x32x32_i8(a0, b1, acc[0][1], 0, 0, 0);
            acc[1][0] = __builtin_amdgcn_mfma_i32_32x32x32_i8(a1, b0, acc[1][0], 0, 0, 0);
            acc[1][1] = __builtin_amdgcn_mfma_i32_32x32x32_i8(a1, b1, acc[1][1], 0, 0, 0);
            acc[2][0] = __builtin_amdgcn_mfma_i32_32x32x32_i8(a2, b0, acc[2][0], 0, 0, 0);
            acc[2][1] = __builtin_amdgcn_mfma_i32_32x32x32_i8(a2, b1, acc[2][1], 0, 0, 0);
            acc[3][0] = __builtin_amdgcn_mfma_i32_32x32x32_i8(a3, b0, acc[3][0], 0, 0, 0);
            acc[3][1] = __builtin_amdgcn_mfma_i32_32x32x32_i8(a3, b1, acc[3][1], 0, 0, 0);
            __builtin_amdgcn_s_setprio(0);
            __builtin_amdgcn_s_barrier();
        }

        // ---------- phase 1 (k-step s=1, plane = 2+hi) ----------
        {
            const signed char* A = Ab + (2 + hi) * 4096;
            const signed char* B = Bb + (2 + hi) * 4096;
            v4i a0 = *(const v4i*)(A + aOff);
            v4i a1 = *(const v4i*)(A + aOff + 512);
            v4i a2 = *(const v4i*)(A + aOff + 1024);
            v4i a3 = *(const v4i*)(A + aOff + 1536);
            v4i b0 = *(const v4i*)(B + bOff);
            v4i b1 = *(const v4i*)(B + bOff + 512);
            if (kt < NT - 3) stageB((kt + 3) & 3, kt + 3);
            __builtin_amdgcn_s_barrier();
            __builtin_amdgcn_s_setprio(1);
            acc[0][0] = __builtin_amdgcn_mfma_i32_32x32x32_i8(a0, b0, acc[0][0], 0, 0, 0);
            acc[0][1] = __builtin_amdgcn_mfma_i32_32x32x32_i8(a0, b1, acc[0][1], 0, 0, 0);
            acc[1][0] = __builtin_amdgcn_mfma_i32_32x32x32_i8(a1, b0, acc[1][0], 0, 0, 0);
            acc[1][1] = __builtin_amdgcn_mfma_i32_32x32x32_i8(a1, b1, acc[1][1], 0, 0, 0);
            acc[2][0] = __builtin_amdgcn_mfma_i32_32x32x32_i8(a2, b0, acc[2][0], 0, 0, 0);
            acc[2][1] = __builtin_amdgcn_mfma_i32_32x32x32_i8(a2, b1, acc[2][1], 0, 0, 0);
            acc[3][0] = __builtin_amdgcn_mfma_i32_32x32x32_i8(a3, b0, acc[3][0], 0, 0, 0);
            acc[3][1] = __builtin_amdgcn_mfma_i32_32x32x32_i8(a3, b1, acc[3][1], 0, 0, 0);
            __builtin_amdgcn_s_setprio(0);
            // tile boundary: wait for tile kt+1's staging (counted, never early-drain)
            if (kt < NT - 1) {
                if (kt <= NT - 4)      asm volatile("s_waitcnt vmcnt(8)" ::: "memory");
                else if (kt == NT - 3) asm volatile("s_waitcnt vmcnt(4)" ::: "memory");
                else                   asm volatile("s_waitcnt vmcnt(0)" ::: "memory");
            }
            __builtin_amdgcn_s_barrier();
        }
    }

    // ---- epilogue: out = fs*acc + mul*bias ----
    // C/D layout (32x32): col = lane&31, row = (r&3) + 8*(r>>2) + 4*(lane>>5)
    const float fm = mulv[0];
    const float fs = fm * (__uint_as_float(scales[0]) / 128.0f)
                        * (__uint_as_float(scales[1]) / 127.0f);
    const int colb = bn * 256 + wc * 64 + ln;
    const int hi4  = hi * 4;
#pragma unroll
    for (int nt = 0; nt < 2; ++nt) {
        const int ocol = colb + nt * 32;
        const float bv = bias[ocol] * fm;
#pragma unroll
        for (int mt = 0; mt < 4; ++mt) {
            float* op = out + (size_t)(bm * 256 + wr * 128 + mt * 32) * NDIM + ocol;
#pragma unroll
            for (int r = 0; r < 16; ++r) {
                const int row = (r & 3) + 8 * (r >> 2) + hi4;
                op[(size_t)row * NDIM] = fs * (float)acc[mt][nt][r] + bv;
            }
        }
    }
}

extern "C" void kernel_launch(void* const* d_in, const int* in_sizes, int n_in,
                              void* d_out, int out_size, void* d_ws, size_t ws_size,
                              hipStream_t stream) {
    const float* x    = (const float*)d_in[0];
    const float* wgt  = (const float*)d_in[1];
    const float* bias = (const float*)d_in[2];
    const float* mulv = (const float*)d_in[3];
    float* out = (float*)d_out;

    unsigned* scales = (unsigned*)d_ws;
    signed char* qxp = (signed char*)d_ws + 256;
    signed char* qwp = qxp + (size_t)MDIM * KDIM;

    const int nx4 = MDIM * KDIM / 4;  // 2M float4
    const int nw4 = NDIM * KDIM / 4;  // 4M float4

    init_scales<<<1, 64, 0, stream>>>(scales);
    absmax2<<<3072, 256, 0, stream>>>((const float4*)x, nx4,
                                      (const float4*)wgt, nw4, scales);
    quant2<<<3072, 256, 0, stream>>>((const float4*)x, (v4i*)qxp,
                                     (const float4*)wgt, (v4i*)qwp, scales);

    gemm_i8<<<512, 512, 0, stream>>>(qxp, qwp, bias, mulv, scales, out);
}

// Round 4
// 166.062 us; speedup vs baseline: 1.0586x; 1.0586x over previous
//
#include <hip/hip_runtime.h>

// Int8 fake-quant linear (exact integer accumulation):
//   sx = max|x|/128; qx = clamp(rint(x/sx),-128,127)
//   sw = max|w|/127; qw = clamp(rint(w/sw),-127,127)
//   out = mul * (sx*sw*(qx @ qw^T) + bias)
//
// qx/qw stored PERMUTED in workspace, in LDS chunk-plane order:
//   v4i index = ((blk*32 + kt)*4 + c)*256 + r
//   holds bytes [kt*64 + c*16 .. +15] of row blk*256+r.
// -> staging is a linear contiguous copy (global_load_lds, lane-linear dest)
// -> fragment reads are 32-lane-contiguous (verified: 0 bank conflicts)

typedef int v4i  __attribute__((ext_vector_type(4)));
typedef int v16i __attribute__((ext_vector_type(16)));

#define MDIM 4096
#define NDIM 8192
#define KDIM 2048
#define NT   (KDIM / 64)   // 32 K-tiles of BK=64 int8

typedef __attribute__((address_space(1))) void* gas_ptr;   // global
typedef __attribute__((address_space(3))) void* las_ptr;   // LDS

// ---------------- init: zero the two absmax slots ----------------
__global__ void init_scales(unsigned* s) {
    if (threadIdx.x < 2) s[threadIdx.x] = 0u;
}

// ---------------- fused absmax over x and w ----------------
#define XBLK 1024
__global__ void absmax2(const float4* __restrict__ x, int nx4,
                        const float4* __restrict__ w, int nw4,
                        unsigned* __restrict__ out) {
    const bool isx = blockIdx.x < XBLK;
    const float4* in = isx ? x : w;
    const int n4 = isx ? nx4 : nw4;
    const int nb = isx ? XBLK : (gridDim.x - XBLK);
    const int b  = isx ? blockIdx.x : (blockIdx.x - XBLK);
    float m = 0.0f;
    for (int i = b * blockDim.x + threadIdx.x; i < n4; i += nb * blockDim.x) {
        float4 v = in[i];
        m = fmaxf(m, fmaxf(fmaxf(fabsf(v.x), fabsf(v.y)),
                           fmaxf(fabsf(v.z), fabsf(v.w))));
    }
#pragma unroll
    for (int off = 32; off > 0; off >>= 1)
        m = fmaxf(m, __shfl_xor(m, off, 64));
    __shared__ float wm[4];
    if ((threadIdx.x & 63) == 0) wm[threadIdx.x >> 6] = m;
    __syncthreads();
    if (threadIdx.x == 0) {
        float mm = fmaxf(fmaxf(wm[0], wm[1]), fmaxf(wm[2], wm[3]));
        atomicMax(out + (isx ? 0 : 1), __float_as_uint(mm));
    }
}

// ---------------- fused quantize into PERMUTED int8 layout ----------------
// v4i idx: c = idx&3, r = (idx>>2)&255, kt = (idx>>10)&31, blk = idx>>15.
// Wave coalescing: 64 lanes = 16 rows x (4 chunks c) -> reads cover 16
// contiguous 256B segments; writes (o = slab + c*256 + r) form 4 contiguous
// 256B clusters (16 consecutive v4i per same-c lane group).
__global__ void quant2(const float4* __restrict__ x, v4i* __restrict__ qxp,
                       const float4* __restrict__ w, v4i* __restrict__ qwp,
                       const unsigned* __restrict__ scales) {
    const bool isx = blockIdx.x < XBLK;
    const float4* in = isx ? x : w;
    v4i* outp = isx ? qxp : qwp;
    const int total = isx ? (MDIM * KDIM / 16) : (NDIM * KDIM / 16);
    const int nb = isx ? XBLK : (gridDim.x - XBLK);
    const int b  = isx ? blockIdx.x : (blockIdx.x - XBLK);
    const float s  = __uint_as_float(scales[isx ? 0 : 1]) / (isx ? 128.0f : 127.0f);
    const float lo = isx ? -128.0f : -127.0f;
    for (int idx = b * blockDim.x + threadIdx.x; idx < total; idx += nb * blockDim.x) {
        const int c   = idx & 3;
        const int r   = (idx >> 2) & 255;
        const int kt  = (idx >> 10) & 31;
        const int blk = idx >> 15;
        const int row = blk * 256 + r;
        const float4* src = in + (size_t)row * (KDIM / 4) + kt * 16 + c * 4;
        int q[4];
#pragma unroll
        for (int j = 0; j < 4; ++j) {
            float4 v = src[j];
            int b0 = (int)fminf(fmaxf(rintf(v.x / s), lo), 127.0f);
            int b1 = (int)fminf(fmaxf(rintf(v.y / s), lo), 127.0f);
            int b2 = (int)fminf(fmaxf(rintf(v.z / s), lo), 127.0f);
            int b3 = (int)fminf(fmaxf(rintf(v.w / s), lo), 127.0f);
            q[j] = (b0 & 255) | ((b1 & 255) << 8) | ((b2 & 255) << 16) | (b3 << 24);
        }
        v4i qq; qq[0] = q[0]; qq[1] = q[1]; qq[2] = q[2]; qq[3] = q[3];
        outp[((size_t)(blk * 32 + kt) * 4 + c) * 256 + r] = qq;
    }
}

// ---------------- int8 MFMA GEMM, 256x256 tile, 4-deep ring ----------------
// 8 waves (2M x 4N); wave output 128x64 = 4x2 mfma_i32_32x32x32_i8.
// LDS per buffer: A,B each 4 chunk-planes x 256 rows x 16B (16 KB); 4 bufs = 128 KiB.
// Per K-tile (ONE barrier): {counted vmcnt(8/4/0); s_barrier; stage tile kt+3;
// 12 ds_read_b128 (both k-steps, conflict-free); setprio(1); 32 MFMA; setprio(0)}.
// LDS pipe (~1.1k cyc) and matrix pipe (~1k cyc) overlap across the 2 waves/SIMD.
__global__ __launch_bounds__(512, 2) void gemm_i8(
    const signed char* __restrict__ qxp, const signed char* __restrict__ qwp,
    const float* __restrict__ bias, const float* __restrict__ mulv,
    const unsigned* __restrict__ scales, float* __restrict__ out) {
    __shared__ signed char ldsA[4][16384];
    __shared__ signed char ldsB[4][16384];

    const int t    = threadIdx.x;
    const int lane = t & 63;
    const int ln   = lane & 31;
    const int hi   = lane >> 5;
    const int w    = t >> 6;      // 0..7
    const int wr   = w >> 2;      // 0..1  (M half)
    const int wc   = w & 3;       // 0..3  (N quarter)

    // XCD-aware swizzle: 512 workgroups, 512 % 8 == 0 -> simple bijection.
    const int orig = blockIdx.x;
    const int wg   = ((orig & 7) << 6) | (orig >> 3);
    const int bm   = wg >> 5;     // 0..15
    const int bn   = wg & 31;     // 0..31

    // ---- staging: linear contiguous copy of 16KB tile slabs ----
    const signed char* srcA = qxp + (size_t)bm * (32 * 16384);
    const signed char* srcB = qwp + (size_t)bn * (32 * 16384);
    signed char* dA = &ldsA[0][0] + t * 16;   // wave-uniform base + lane*16
    signed char* dB = &ldsB[0][0] + t * 16;

    auto stage = [&](int buf, int kt) {
        const signed char* sa = srcA + kt * 16384 + t * 16;
        const signed char* sb = srcB + kt * 16384 + t * 16;
        __builtin_amdgcn_global_load_lds((gas_ptr)sa,          (las_ptr)(dA + buf * 16384),        16, 0, 0);
        __builtin_amdgcn_global_load_lds((gas_ptr)(sa + 8192), (las_ptr)(dA + buf * 16384 + 8192), 16, 0, 0);
        __builtin_amdgcn_global_load_lds((gas_ptr)sb,          (las_ptr)(dB + buf * 16384),        16, 0, 0);
        __builtin_amdgcn_global_load_lds((gas_ptr)(sb + 8192), (las_ptr)(dB + buf * 16384 + 8192), 16, 0, 0);
    };

    // ---- fragment offsets (chunk-plane: plane = 2*s+hi, 32-lane contiguous) ----
    const int aOff = (wr * 128 + ln) * 16;   // + mt*512 + plane*4096
    const int bOff = (wc * 64  + ln) * 16;   // + nt*512 + plane*4096

    v16i acc[4][2];
#pragma unroll
    for (int mt = 0; mt < 4; ++mt)
#pragma unroll
        for (int nt = 0; nt < 2; ++nt)
#pragma unroll
            for (int r = 0; r < 16; ++r) acc[mt][nt][r] = 0;

    // ---- prologue: 3 tiles in flight ----
    stage(0, 0);
    stage(1, 1);
    stage(2, 2);

    for (int kt = 0; kt < NT; ++kt) {
        // counted wait for tile kt's staging (never early-drain)
        if (kt <= NT - 3)      asm volatile("s_waitcnt vmcnt(8)" ::: "memory");
        else if (kt == NT - 2) asm volatile("s_waitcnt vmcnt(4)" ::: "memory");
        else                   asm volatile("s_waitcnt vmcnt(0)" ::: "memory");
        __builtin_amdgcn_s_barrier();
        if (kt < NT - 3) stage((kt + 3) & 3, kt + 3);

        const int buf = kt & 3;
        const signed char* A0 = &ldsA[buf][0] + hi * 4096;        // k-step 0
        const signed char* B0 = &ldsB[buf][0] + hi * 4096;
        const signed char* A1 = &ldsA[buf][0] + (2 + hi) * 4096;  // k-step 1
        const signed char* B1 = &ldsB[buf][0] + (2 + hi) * 4096;

        v4i a0[4], a1[4], b0[2], b1[2];
#pragma unroll
        for (int mt = 0; mt < 4; ++mt) a0[mt] = *(const v4i*)(A0 + aOff + mt * 512);
#pragma unroll
        for (int nt = 0; nt < 2; ++nt) b0[nt] = *(const v4i*)(B0 + bOff + nt * 512);
#pragma unroll
        for (int mt = 0; mt < 4; ++mt) a1[mt] = *(const v4i*)(A1 + aOff + mt * 512);
#pragma unroll
        for (int nt = 0; nt < 2; ++nt) b1[nt] = *(const v4i*)(B1 + bOff + nt * 512);

        __builtin_amdgcn_s_setprio(1);
#pragma unroll
        for (int mt = 0; mt < 4; ++mt)
#pragma unroll
            for (int nt = 0; nt < 2; ++nt)
                acc[mt][nt] = __builtin_amdgcn_mfma_i32_32x32x32_i8(
                    a0[mt], b0[nt], acc[mt][nt], 0, 0, 0);
#pragma unroll
        for (int mt = 0; mt < 4; ++mt)
#pragma unroll
            for (int nt = 0; nt < 2; ++nt)
                acc[mt][nt] = __builtin_amdgcn_mfma_i32_32x32x32_i8(
                    a1[mt], b1[nt], acc[mt][nt], 0, 0, 0);
        __builtin_amdgcn_s_setprio(0);
    }

    // ---- epilogue: out = fs*acc + mul*bias ----
    // C/D layout (32x32): col = lane&31, row = (r&3) + 8*(r>>2) + 4*(lane>>5)
    const float fm = mulv[0];
    const float fs = fm * (__uint_as_float(scales[0]) / 128.0f)
                        * (__uint_as_float(scales[1]) / 127.0f);
    const int colb = bn * 256 + wc * 64 + ln;
    const int hi4  = hi * 4;
#pragma unroll
    for (int nt = 0; nt < 2; ++nt) {
        const int ocol = colb + nt * 32;
        const float bv = bias[ocol] * fm;
#pragma unroll
        for (int mt = 0; mt < 4; ++mt) {
            float* op = out + (size_t)(bm * 256 + wr * 128 + mt * 32) * NDIM + ocol;
#pragma unroll
            for (int r = 0; r < 16; ++r) {
                const int row = (r & 3) + 8 * (r >> 2) + hi4;
                op[(size_t)row * NDIM] = fs * (float)acc[mt][nt][r] + bv;
            }
        }
    }
}

extern "C" void kernel_launch(void* const* d_in, const int* in_sizes, int n_in,
                              void* d_out, int out_size, void* d_ws, size_t ws_size,
                              hipStream_t stream) {
    const float* x    = (const float*)d_in[0];
    const float* wgt  = (const float*)d_in[1];
    const float* bias = (const float*)d_in[2];
    const float* mulv = (const float*)d_in[3];
    float* out = (float*)d_out;

    unsigned* scales = (unsigned*)d_ws;
    signed char* qxp = (signed char*)d_ws + 256;
    signed char* qwp = qxp + (size_t)MDIM * KDIM;

    const int nx4 = MDIM * KDIM / 4;  // 2M float4
    const int nw4 = NDIM * KDIM / 4;  // 4M float4

    init_scales<<<1, 64, 0, stream>>>(scales);
    absmax2<<<3072, 256, 0, stream>>>((const float4*)x, nx4,
                                      (const float4*)wgt, nw4, scales);
    quant2<<<3072, 256, 0, stream>>>((const float4*)x, (v4i*)qxp,
                                     (const float4*)wgt, (v4i*)qwp, scales);

    gemm_i8<<<512, 512, 0, stream>>>(qxp, qwp, bias, mulv, scales, out);
}

// Round 5
// 157.446 us; speedup vs baseline: 1.1165x; 1.0547x over previous
//
#include <hip/hip_runtime.h>

// Int8 fake-quant linear (exact integer accumulation):
//   sx = max|x|/128; qx = clamp(rint(x/sx),-128,127)
//   sw = max|w|/127; qw = clamp(rint(w/sw),-127,127)
//   out = mul * (sx*sw*(qx @ qw^T) + bias)
//
// qx/qw stored PERMUTED in workspace, in LDS chunk-plane order:
//   v4i index = ((blk*32 + kt)*4 + c)*256 + r
//   holds bytes [kt*64 + c*16 .. +15] of row blk*256+r.
// -> staging is a linear contiguous copy (global_load_lds, lane-linear dest)
// -> fragment reads are 32-lane-contiguous (verified: 0 bank conflicts)

typedef int v4i  __attribute__((ext_vector_type(4)));
typedef int v16i __attribute__((ext_vector_type(16)));

#define MDIM 4096
#define NDIM 8192
#define KDIM 2048
#define NT   (KDIM / 64)   // 32 K-tiles of BK=64 int8

typedef __attribute__((address_space(1))) void* gas_ptr;   // global
typedef __attribute__((address_space(3))) void* las_ptr;   // LDS

// ---------------- init: zero the two absmax slots ----------------
__global__ void init_scales(unsigned* s) {
    if (threadIdx.x < 2) s[threadIdx.x] = 0u;
}

// ---------------- fused absmax over x and w ----------------
#define XBLK 1024
__global__ void absmax2(const float4* __restrict__ x, int nx4,
                        const float4* __restrict__ w, int nw4,
                        unsigned* __restrict__ out) {
    const bool isx = blockIdx.x < XBLK;
    const float4* in = isx ? x : w;
    const int n4 = isx ? nx4 : nw4;
    const int nb = isx ? XBLK : (gridDim.x - XBLK);
    const int b  = isx ? blockIdx.x : (blockIdx.x - XBLK);
    float m = 0.0f;
    for (int i = b * blockDim.x + threadIdx.x; i < n4; i += nb * blockDim.x) {
        float4 v = in[i];
        m = fmaxf(m, fmaxf(fmaxf(fabsf(v.x), fabsf(v.y)),
                           fmaxf(fabsf(v.z), fabsf(v.w))));
    }
#pragma unroll
    for (int off = 32; off > 0; off >>= 1)
        m = fmaxf(m, __shfl_xor(m, off, 64));
    __shared__ float wm[4];
    if ((threadIdx.x & 63) == 0) wm[threadIdx.x >> 6] = m;
    __syncthreads();
    if (threadIdx.x == 0) {
        float mm = fmaxf(fmaxf(wm[0], wm[1]), fmaxf(wm[2], wm[3]));
        atomicMax(out + (isx ? 0 : 1), __float_as_uint(mm));
    }
}

// ---------------- fused quantize into PERMUTED int8 layout ----------------
// v4i idx: c = idx&3, r = (idx>>2)&255, kt = (idx>>10)&31, blk = idx>>15.
// Wave coalescing: 64 lanes = 16 rows x (4 chunks c) -> reads cover 16
// contiguous 256B segments; writes form 4 contiguous 256B clusters.
__global__ void quant2(const float4* __restrict__ x, v4i* __restrict__ qxp,
                       const float4* __restrict__ w, v4i* __restrict__ qwp,
                       const unsigned* __restrict__ scales) {
    const bool isx = blockIdx.x < XBLK;
    const float4* in = isx ? x : w;
    v4i* outp = isx ? qxp : qwp;
    const int total = isx ? (MDIM * KDIM / 16) : (NDIM * KDIM / 16);
    const int nb = isx ? XBLK : (gridDim.x - XBLK);
    const int b  = isx ? blockIdx.x : (blockIdx.x - XBLK);
    const float s  = __uint_as_float(scales[isx ? 0 : 1]) / (isx ? 128.0f : 127.0f);
    const float lo = isx ? -128.0f : -127.0f;
    for (int idx = b * blockDim.x + threadIdx.x; idx < total; idx += nb * blockDim.x) {
        const int c   = idx & 3;
        const int r   = (idx >> 2) & 255;
        const int kt  = (idx >> 10) & 31;
        const int blk = idx >> 15;
        const int row = blk * 256 + r;
        const float4* src = in + (size_t)row * (KDIM / 4) + kt * 16 + c * 4;
        int q[4];
#pragma unroll
        for (int j = 0; j < 4; ++j) {
            float4 v = src[j];
            int b0 = (int)fminf(fmaxf(rintf(v.x / s), lo), 127.0f);
            int b1 = (int)fminf(fmaxf(rintf(v.y / s), lo), 127.0f);
            int b2 = (int)fminf(fmaxf(rintf(v.z / s), lo), 127.0f);
            int b3 = (int)fminf(fmaxf(rintf(v.w / s), lo), 127.0f);
            q[j] = (b0 & 255) | ((b1 & 255) << 8) | ((b2 & 255) << 16) | (b3 << 24);
        }
        v4i qq; qq[0] = q[0]; qq[1] = q[1]; qq[2] = q[2]; qq[3] = q[3];
        outp[((size_t)(blk * 32 + kt) * 4 + c) * 256 + r] = qq;
    }
}

// ---------------- int8 MFMA GEMM, 256x256 tile, 4-deep ring ----------------
// 8 waves (2M x 4N); wave output 128x64 = 4x2 mfma_i32_32x32x32_i8.
// LDS per buffer: A,B each 4 chunk-planes x 256 rows x 16B (16 KB); 4 bufs = 128 KiB.
// Schedule: 2 K-tiles per outer iter; each tile = ONE phase of the proven R3
// shape: {12 ds_read_b128; stage tile kt+3 (4 gload_lds); s_barrier;
// setprio(1); 16 MFMA; setprio(0); s_barrier}. Counted vmcnt(4) once per
// 2 tiles (tiles 2j,2j+1 resident; 2j+4 still in flight) — never drained
// to 0 until the last tile.
__global__ __launch_bounds__(512, 2) void gemm_i8(
    const signed char* __restrict__ qxp, const signed char* __restrict__ qwp,
    const float* __restrict__ bias, const float* __restrict__ mulv,
    const unsigned* __restrict__ scales, float* __restrict__ out) {
    __shared__ signed char ldsA[4][16384];
    __shared__ signed char ldsB[4][16384];

    const int t    = threadIdx.x;
    const int lane = t & 63;
    const int ln   = lane & 31;
    const int hi   = lane >> 5;
    const int w    = t >> 6;      // 0..7
    const int wr   = w >> 2;      // 0..1  (M half)
    const int wc   = w & 3;       // 0..3  (N quarter)

    // XCD-aware swizzle: 512 workgroups, 512 % 8 == 0 -> simple bijection.
    const int orig = blockIdx.x;
    const int wg   = ((orig & 7) << 6) | (orig >> 3);
    const int bm   = wg >> 5;     // 0..15
    const int bn   = wg & 31;     // 0..31

    // ---- staging: linear contiguous copy of 16KB tile slabs ----
    const signed char* srcA = qxp + (size_t)bm * (32 * 16384);
    const signed char* srcB = qwp + (size_t)bn * (32 * 16384);
    signed char* dA = &ldsA[0][0] + t * 16;   // wave-uniform base + lane*16
    signed char* dB = &ldsB[0][0] + t * 16;

    auto stage = [&](int buf, int kt) {
        const signed char* sa = srcA + kt * 16384 + t * 16;
        const signed char* sb = srcB + kt * 16384 + t * 16;
        __builtin_amdgcn_global_load_lds((gas_ptr)sa,          (las_ptr)(dA + buf * 16384),        16, 0, 0);
        __builtin_amdgcn_global_load_lds((gas_ptr)(sa + 8192), (las_ptr)(dA + buf * 16384 + 8192), 16, 0, 0);
        __builtin_amdgcn_global_load_lds((gas_ptr)sb,          (las_ptr)(dB + buf * 16384),        16, 0, 0);
        __builtin_amdgcn_global_load_lds((gas_ptr)(sb + 8192), (las_ptr)(dB + buf * 16384 + 8192), 16, 0, 0);
    };

    // ---- fragment offsets (chunk-plane: plane = 2*s+hi, 32-lane contiguous) ----
    const int aOff = (wr * 128 + ln) * 16;   // + mt*512 + plane*4096
    const int bOff = (wc * 64  + ln) * 16;   // + nt*512 + plane*4096

    v16i acc[4][2];
#pragma unroll
    for (int mt = 0; mt < 4; ++mt)
#pragma unroll
        for (int nt = 0; nt < 2; ++nt)
#pragma unroll
            for (int r = 0; r < 16; ++r) acc[mt][nt][r] = 0;

    // One full-tile phase, R3 shape: reads -> stage -> bar -> prio1 16 MFMA prio0.
    // Caller appends the trailing barrier (optionally preceded by a vmcnt).
    auto phase = [&](int kt, int stageKt) {
        const int buf = kt & 3;
        const signed char* A0 = &ldsA[buf][0] + hi * 4096;        // k-step 0
        const signed char* B0 = &ldsB[buf][0] + hi * 4096;
        const signed char* A1 = &ldsA[buf][0] + (2 + hi) * 4096;  // k-step 1
        const signed char* B1 = &ldsB[buf][0] + (2 + hi) * 4096;

        v4i a0[4], a1[4], b0[2], b1[2];
#pragma unroll
        for (int mt = 0; mt < 4; ++mt) a0[mt] = *(const v4i*)(A0 + aOff + mt * 512);
#pragma unroll
        for (int nt = 0; nt < 2; ++nt) b0[nt] = *(const v4i*)(B0 + bOff + nt * 512);
#pragma unroll
        for (int mt = 0; mt < 4; ++mt) a1[mt] = *(const v4i*)(A1 + aOff + mt * 512);
#pragma unroll
        for (int nt = 0; nt < 2; ++nt) b1[nt] = *(const v4i*)(B1 + bOff + nt * 512);

        if (stageKt < NT) stage(stageKt & 3, stageKt);
        __builtin_amdgcn_s_barrier();
        __builtin_amdgcn_s_setprio(1);
#pragma unroll
        for (int mt = 0; mt < 4; ++mt)
#pragma unroll
            for (int nt = 0; nt < 2; ++nt)
                acc[mt][nt] = __builtin_amdgcn_mfma_i32_32x32x32_i8(
                    a0[mt], b0[nt], acc[mt][nt], 0, 0, 0);
#pragma unroll
        for (int mt = 0; mt < 4; ++mt)
#pragma unroll
            for (int nt = 0; nt < 2; ++nt)
                acc[mt][nt] = __builtin_amdgcn_mfma_i32_32x32x32_i8(
                    a1[mt], b1[nt], acc[mt][nt], 0, 0, 0);
        __builtin_amdgcn_s_setprio(0);
    };

    // ---- prologue: 3 tiles in flight; tiles 0,1 resident before loop ----
    stage(0, 0);
    stage(1, 1);
    stage(2, 2);
    asm volatile("s_waitcnt vmcnt(4)" ::: "memory");   // tiles 0,1 done
    __builtin_amdgcn_s_barrier();

    for (int j = 0; j < 15; ++j) {
        phase(2 * j, 2 * j + 3);
        __builtin_amdgcn_s_barrier();
        phase(2 * j + 1, 2 * j + 4);
        // tiles 2j+2, 2j+3 resident for next iter; 2j+4 stays in flight
        asm volatile("s_waitcnt vmcnt(4)" ::: "memory");
        __builtin_amdgcn_s_barrier();
    }
    phase(30, NT);                                     // no staging left
    asm volatile("s_waitcnt vmcnt(0)" ::: "memory");   // tile 31 done
    __builtin_amdgcn_s_barrier();
    phase(31, NT);

    // ---- epilogue: out = fs*acc + mul*bias ----
    // C/D layout (32x32): col = lane&31, row = (r&3) + 8*(r>>2) + 4*(lane>>5)
    const float fm = mulv[0];
    const float fs = fm * (__uint_as_float(scales[0]) / 128.0f)
                        * (__uint_as_float(scales[1]) / 127.0f);
    const int colb = bn * 256 + wc * 64 + ln;
    const int hi4  = hi * 4;
#pragma unroll
    for (int nt = 0; nt < 2; ++nt) {
        const int ocol = colb + nt * 32;
        const float bv = bias[ocol] * fm;
#pragma unroll
        for (int mt = 0; mt < 4; ++mt) {
            float* op = out + (size_t)(bm * 256 + wr * 128 + mt * 32) * NDIM + ocol;
#pragma unroll
            for (int r = 0; r < 16; ++r) {
                const int row = (r & 3) + 8 * (r >> 2) + hi4;
                op[(size_t)row * NDIM] = fs * (float)acc[mt][nt][r] + bv;
            }
        }
    }
}

extern "C" void kernel_launch(void* const* d_in, const int* in_sizes, int n_in,
                              void* d_out, int out_size, void* d_ws, size_t ws_size,
                              hipStream_t stream) {
    const float* x    = (const float*)d_in[0];
    const float* wgt  = (const float*)d_in[1];
    const float* bias = (const float*)d_in[2];
    const float* mulv = (const float*)d_in[3];
    float* out = (float*)d_out;

    unsigned* scales = (unsigned*)d_ws;
    signed char* qxp = (signed char*)d_ws + 256;
    signed char* qwp = qxp + (size_t)MDIM * KDIM;

    const int nx4 = MDIM * KDIM / 4;  // 2M float4
    const int nw4 = NDIM * KDIM / 4;  // 4M float4

    init_scales<<<1, 64, 0, stream>>>(scales);
    absmax2<<<3072, 256, 0, stream>>>((const float4*)x, nx4,
                                      (const float4*)wgt, nw4, scales);
    quant2<<<3072, 256, 0, stream>>>((const float4*)x, (v4i*)qxp,
                                     (const float4*)wgt, (v4i*)qwp, scales);

    gemm_i8<<<512, 512, 0, stream>>>(qxp, qwp, bias, mulv, scales, out);
}